// Round 13
// baseline (172.904 us; speedup 1.0000x reference)
//
#include <hip/hip_runtime.h>
#include <hip/hip_bf16.h>
#include <cstdint>

#define DEV __device__ __forceinline__

typedef __attribute__((ext_vector_type(8))) __bf16 bf16x8;
typedef __attribute__((ext_vector_type(4))) float floatx4;
typedef __attribute__((ext_vector_type(4))) short shortx4;
typedef __attribute__((ext_vector_type(8))) short shortx8;

// 0.125 (= dim_head^-0.5) * log2(e): fold scale AND base-2 conversion into Q.
constexpr float QSCALE = 0.18033688011112042f;

// Manual RTNE f32->bf16 -- kept for prep (x, weights) and attn output.
// Rounds 6/7 proved gfx950's v_cvt_pk_bf16_f32 is NOT RTNE (1 output-ULP
// systematic bias, 0.03 absmax, 5x threshold) -- never reintroduce it.
DEV unsigned short f2b(float f) {
  union { float f; unsigned u; } v; v.f = f;
  return (unsigned short)((v.u + 0x7fffu + ((v.u >> 16) & 1u)) >> 16);  // RTNE
}

// Half-up rounding (no tie-to-even): differs from RTNE only on exact ties
// (prob ~2^-16/value), error still <= 0.5 ULP -- validated rounds 9/11
// (absmax unchanged at 0.00195). ~3x fewer VALU ops than manual RTNE.
DEV unsigned short f2bp(float f) {
  union { float f; unsigned u; } v; v.f = f;
  return (unsigned short)((v.u + 0x8000u) >> 16);
}

DEV unsigned pk2p(float a, float b) {
  union { float f; unsigned u; } x, y; x.f = a; y.f = b;
  return ((x.u + 0x8000u) >> 16) | ((y.u + 0x8000u) & 0xffff0000u);
}

#if defined(__has_builtin) && __has_builtin(__builtin_amdgcn_exp2f)
DEV float fexp2(float x) { return __builtin_amdgcn_exp2f(x); }
#else
DEV float fexp2(float x) { return exp2f(x); }
#endif

DEV floatx4 mfma16(bf16x8 a, bf16x8 b, floatx4 c) {
  return __builtin_amdgcn_mfma_f32_16x16x32_bf16(a, b, c, 0, 0, 0);
}

#define GLD_LDS16(gp, lp)                                                          \
  __builtin_amdgcn_global_load_lds(                                                \
      (const __attribute__((address_space(1))) void*)(gp),                         \
      (__attribute__((address_space(3))) void*)(lp), 16, 0, 0)

// ---------------------------------------------------------------- prep
// Fused: bf16-convert of x (blocks [0,4096)) + transpose-convert of both
// weight matrices (blocks [4096,5120)). One dispatch instead of two.
// Exact RTNE here (inputs feed two GEMM stages -- keep rounding canonical).
__global__ void prep(const float* __restrict__ x,
                     const float* __restrict__ w_qkv,
                     const float* __restrict__ w_out,
                     unsigned short* __restrict__ xb,
                     unsigned short* __restrict__ wqkvt,
                     unsigned short* __restrict__ woutt) {
  __shared__ float tile[32][33];
  if (blockIdx.x < 4096) {
    int i = blockIdx.x * 256 + threadIdx.x;
    floatx4 f = ((const floatx4*)x)[i];
    shortx4 s;
    s[0] = (short)f2b(f[0]); s[1] = (short)f2b(f[1]);
    s[2] = (short)f2b(f[2]); s[3] = (short)f2b(f[3]);
    ((shortx4*)xb)[i] = s;
    return;
  }
  int id = blockIdx.x - 4096;
  int bxr = id & 63, by = id >> 6;
  const float* in; unsigned short* out; int C, bx;
  if (bxr < 48) { in = w_qkv; out = wqkvt; C = 1536; bx = bxr; }
  else { in = w_out; out = woutt; C = 512; bx = bxr - 48; }
  const int R = 512;
  int tx = threadIdx.x & 31, ty = threadIdx.x >> 5;
  int r0 = by * 32, c0 = bx * 32;
#pragma unroll
  for (int i = 0; i < 4; i++) {
    int rr = ty + i * 8;
    tile[rr][tx] = in[(size_t)(r0 + rr) * C + c0 + tx];
  }
  __syncthreads();
#pragma unroll
  for (int i = 0; i < 4; i++) {
    int rr = ty + i * 8;
    out[(size_t)(c0 + rr) * R + r0 + tx] = f2b(tile[tx][rr]);
  }
}

// ---------------------------------------------------------------- QKV GEMM
// C = A * Bt^T. A [8192][512], Bt [1536][512]. 128x128 tile, BK=32, dbuf.
// grid (12,64) = 768 blocks, 3/CU co-resident. XCD-chunked block swizzle
// (768%8==0 -> bijective): XCD k runs flat ids [96k,96k+96) = 8 M-rows x
// all 12 N-cols -> whole B (1.5 MB) + 8 A-panels (1 MB) stay L2-hot.
// Epilogue conversions use half-up rounding (round-9/11-validated).
// Outputs:
//   q: row-major [bh][2048][64] (pre-scaled by QSCALE)
//   k: row-major [bh][2048][64]
//   v: sigma-permuted frag-major V^T [2048/64][b(4)][kc(2)][lane][8]
__global__ __launch_bounds__(256, 3) void gemm_qkv(
    const unsigned short* __restrict__ A, const unsigned short* __restrict__ Bt,
    unsigned short* __restrict__ qg, unsigned short* __restrict__ kg,
    unsigned short* __restrict__ vf) {
  __shared__ __align__(16) unsigned short smem[17408];  // 34816 B
  const int tid = threadIdx.x;
  const int lane = tid & 63, wid = tid >> 6;
  const int g = lane >> 4, r = lane & 15;
  const int flat = blockIdx.y * 12 + blockIdx.x;
  const int sw = (flat & 7) * 96 + (flat >> 3);
  const int bx = sw % 12, by = sw / 12;
  const int m0 = by * 128, n0 = bx * 128;
  const int wm = (wid & 1) * 64, wn = (wid >> 1) * 64;
  const int K = 512;

  floatx4 acc[4][4] = {};

  int rowA[2], kbA[2];
#pragma unroll
  for (int i = 0; i < 2; i++) {
    int c = i * 256 + tid;
    rowA[i] = c >> 2;
    kbA[i] = (c & 3) ^ ((rowA[i] >> 1) & 3);
  }

#define STAGE_G(kt, b)                                                           \
  {                                                                              \
    _Pragma("unroll") for (int i = 0; i < 2; i++) {                              \
      GLD_LDS16(A + (size_t)(m0 + rowA[i]) * K + (kt) + kbA[i] * 8,              \
                (char*)smem + (b)*8192 + i * 4096 + wid * 1024);                 \
      GLD_LDS16(Bt + (size_t)(n0 + rowA[i]) * K + (kt) + kbA[i] * 8,             \
                (char*)smem + 16384 + (b)*8192 + i * 4096 + wid * 1024);         \
    }                                                                            \
  }

  STAGE_G(0, 0)
  for (int it = 0; it < 16; it++) {
    const int buf = it & 1;
    __syncthreads();
    if (it + 1 < 16) STAGE_G((it + 1) * 32, buf ^ 1)
    const unsigned short* Xs = smem + buf * 4096;
    const unsigned short* Ws = smem + 8192 + buf * 4096;
    bf16x8 a[4], b[4];
#pragma unroll
    for (int t = 0; t < 4; t++) {
      int rw = wm + t * 16 + r;
      a[t] = *(const bf16x8*)(Xs + rw * 32 + (g ^ ((rw >> 1) & 3)) * 8);
      int rb = wn + t * 16 + r;
      b[t] = *(const bf16x8*)(Ws + rb * 32 + (g ^ ((rb >> 1) & 3)) * 8);
    }
#pragma unroll
    for (int mt = 0; mt < 4; mt++)
#pragma unroll
      for (int nt = 0; nt < 4; nt++)
        acc[mt][nt] = mfma16(a[mt], b[nt], acc[mt][nt]);
  }
#undef STAGE_G

  const int which = bx >> 2;  // 0=q 1=k 2=v (block-uniform)
  if (which == 2) {
    // fragment-major sigma-permuted V^T, 16B register stores
    const int tokbase = m0 + wm;  // 64-aligned
    const int bb = tokbase >> 11, vt = (tokbase & 2047) >> 6;
#pragma unroll
    for (int nt = 0; nt < 4; nt++) {
      int vcol = n0 + wn + nt * 16 + r - 1024;
      int h = vcol >> 6;  // uniform over r
      size_t hb = (size_t)(bb * 8 + h) * 131072 + (size_t)vt * 4096 + nt * 1024 +
                  (g * 16 + r) * 8;
#pragma unroll
      for (int kc = 0; kc < 2; kc++) {
        union { unsigned u[4]; shortx8 v; } w;
        w.u[0] = pk2p(acc[2 * kc][nt][0], acc[2 * kc][nt][1]);
        w.u[1] = pk2p(acc[2 * kc][nt][2], acc[2 * kc][nt][3]);
        w.u[2] = pk2p(acc[2 * kc + 1][nt][0], acc[2 * kc + 1][nt][1]);
        w.u[3] = pk2p(acc[2 * kc + 1][nt][2], acc[2 * kc + 1][nt][3]);
        *(shortx8*)(vf + hb + kc * 512) = w.v;
      }
    }
  } else {
    const float sc = (which == 0) ? QSCALE : 1.f;
    unsigned short* dst = (which == 0) ? qg : kg;  // both row-major [bh][n][64]
    __syncthreads();
#pragma unroll
    for (int mt = 0; mt < 4; mt++)
#pragma unroll
      for (int nt = 0; nt < 4; nt++) {
        int col = wn + nt * 16 + r;
#pragma unroll
        for (int e = 0; e < 4; e++)
          smem[(wm + mt * 16 + g * 4 + e) * 136 + col] = f2bp(acc[mt][nt][e] * sc);
      }
    __syncthreads();
#pragma unroll
    for (int it = 0; it < 8; it++) {
      int c = it * 256 + tid;
      int row = c >> 4, cc = c & 15;
      shortx8 v = *(const shortx8*)(smem + row * 136 + cc * 8);
      int gq = n0 + cc * 8;
      int h = (gq >> 6) & 7, d0 = gq & 63;
      int tok = m0 + row, bb = tok >> 11, n = tok & 2047;
      *(shortx8*)(dst + ((size_t)(bb * 8 + h) * 2048 + n) * 64 + d0) = v;
    }
  }
}

// ---------------------------------------------------------------- out GEMM
// C = A * Bt^T + bias. A [8192][512] bf16, Bt [512][512] bf16, out fp32.
// 64x128 tile, BK=32, dbuf, 128 threads / 2 waves, wave = 64x64 output ->
// 16 MFMA per 8 ds_read per iter. LDS: A 8 KiB dbuf + B 16 KiB dbuf =
// 24 KiB -> LB(128,3) ~6 blocks/CU. grid (4,128). LAUNCH WITH 128 THREADS.
// XCD-chunked swizzle (512%8==0 -> bijective digit swap).
__global__ __launch_bounds__(128, 3) void gemm_out(
    const unsigned short* __restrict__ A, const unsigned short* __restrict__ Bt,
    float* __restrict__ outF, const float* __restrict__ bias) {
  __shared__ __align__(16) unsigned short smem[12288];  // 24576 B
  const int tid = threadIdx.x;
  const int lane = tid & 63, wid = tid >> 6;
  const int g = lane >> 4, r = lane & 15;
  const int flat = blockIdx.y * 4 + blockIdx.x;
  const int sw = (flat & 7) * 64 + (flat >> 3);
  const int bx = sw & 3, by = sw >> 2;
  const int m0 = by * 64, n0 = bx * 128;
  const int wn = wid * 64;
  const int K = 512;

  floatx4 acc[4][4] = {};

  int rowA[2], kA[2];
#pragma unroll
  for (int i = 0; i < 2; i++) {
    int c = i * 128 + tid;
    rowA[i] = c >> 2;
    kA[i] = (c & 3) ^ ((rowA[i] >> 1) & 3);
  }
  int rowB[4], kB[4];
#pragma unroll
  for (int i = 0; i < 4; i++) {
    int c = i * 128 + tid;
    rowB[i] = c >> 2;
    kB[i] = (c & 3) ^ ((rowB[i] >> 1) & 3);
  }

#define STAGE_O(kt, b)                                                           \
  {                                                                              \
    _Pragma("unroll") for (int i = 0; i < 2; i++)                                \
        GLD_LDS16(A + (size_t)(m0 + rowA[i]) * K + (kt) + kA[i] * 8,             \
                  (char*)smem + (b)*4096 + i * 2048 + wid * 1024);               \
    _Pragma("unroll") for (int i = 0; i < 4; i++)                                \
        GLD_LDS16(Bt + (size_t)(n0 + rowB[i]) * K + (kt) + kB[i] * 8,            \
                  (char*)smem + 8192 + (b)*8192 + i * 2048 + wid * 1024);        \
  }

  STAGE_O(0, 0)
  for (int it = 0; it < 16; it++) {
    const int buf = it & 1;
    __syncthreads();
    if (it + 1 < 16) STAGE_O((it + 1) * 32, buf ^ 1)
    const unsigned short* Xs = smem + buf * 2048;
    const unsigned short* Ws = smem + 4096 + buf * 4096;
    bf16x8 a[4], b[4];
#pragma unroll
    for (int t = 0; t < 4; t++) {
      int rw = t * 16 + r;
      a[t] = *(const bf16x8*)(Xs + rw * 32 + (g ^ ((rw >> 1) & 3)) * 8);
      int rb = wn + t * 16 + r;
      b[t] = *(const bf16x8*)(Ws + rb * 32 + (g ^ ((rb >> 1) & 3)) * 8);
    }
#pragma unroll
    for (int mt = 0; mt < 4; mt++)
#pragma unroll
      for (int nt = 0; nt < 4; nt++)
        acc[mt][nt] = mfma16(a[mt], b[nt], acc[mt][nt]);
  }
#undef STAGE_O

  float* ftile = (float*)smem;  // [64][68] = 17408 B, fits in 24576
  __syncthreads();
#pragma unroll
  for (int pass = 0; pass < 2; pass++) {
    if (wid == pass) {
#pragma unroll
      for (int mt = 0; mt < 4; mt++)
#pragma unroll
        for (int nt = 0; nt < 4; nt++)
#pragma unroll
          for (int e = 0; e < 4; e++)
            ftile[(mt * 16 + g * 4 + e) * 68 + nt * 16 + r] = acc[mt][nt][e];
    }
    __syncthreads();
#pragma unroll
    for (int it = 0; it < 8; it++) {
      int c = it * 128 + tid;
      int lr = c >> 4, cc = c & 15;
      floatx4 v = *(const floatx4*)(ftile + lr * 68 + cc * 4);
      int col = n0 + pass * 64 + cc * 4;
      v += *(const floatx4*)(bias + col);
      *(floatx4*)(outF + (size_t)(m0 + lr) * 512 + col) = v;
    }
    __syncthreads();
  }
}

// ---------------------------------------------------------------- flash attention
// Round-9 base + T15 2-deep pipeline (round 12, resubmitted after infra
// failure): both QK^T clusters issue back-to-back, then SM0 runs under
// QKT1's MFMA drain and SM1 under PV0's drain (m214v36 mechanism, +7-11%
// there). st0/st1 are separate named arrays (rule #20: static indexing
// only). bv1 issue deferred to after SM0 to cap peak live registers
// (~224 unified < 256 @ LB(256,2)).
// grid 512 blocks XCD-swizzled (each XCD owns 4 bh -> ~3 MB K/V/Q L2-hot),
// LB(256,2), 64 KiB LDS, exactly 2 blocks/CU, no tail.
// Block = 128 q rows x one bh. 4 waves: wq = q-half (64 rows), wk = kv
// stream (128 kv per round, 2 x 64kv subs). K staged via global_load_lds
// into double-buffered XOR-swizzled LDS (256 kv/round, 8 rounds).
// Q row-major direct loads, fzero C-operand QK^T, walking pointers,
// setprio, no-max softmax, pk2p P-packing, l via MFMA(P,1).
__global__ __launch_bounds__(256, 2) void attn(
    const unsigned short* __restrict__ qg, const unsigned short* __restrict__ kg,
    const unsigned short* __restrict__ vf, unsigned short* __restrict__ ao) {
  __shared__ __align__(16) char L[65536];
  unsigned short* Ksm = (unsigned short*)L;  // [2 buf][256 kv][64 d]
  const int tid = threadIdx.x, lane = tid & 63, wid = tid >> 6;
  const int g = lane >> 4, r = lane & 15, r7 = r & 7;
  const int wq = wid & 1, wk = wid >> 1;
  // XCD-bijective swizzle: slot&7 = XCD; each XCD owns bh in [xcd*4, xcd*4+4)
  const int slot = blockIdx.x;
  const int bh = ((slot & 7) << 2) | ((slot >> 3) & 3);
  const int qt = slot >> 5;  // 0..15, 128-row q tile
  const size_t kbase = (size_t)bh * (2048 * 64);  // row-major K and Q
  const size_t fbase = (size_t)bh * 131072;       // frag-major v
  const int srow = lane >> 3;
  const int chunk = (lane & 7) ^ (srow & 7);

  // Q fragments from row-major [bh][2048][64]: B-frag lane (g,r) needs
  // Q[qrow0 + nt*16 + r][kc*32 + g*8 .. +8]
  const unsigned short* qgp =
      qg + kbase + (size_t)(qt * 128 + wq * 64 + r) * 64;
  bf16x8 bq[4][2];
#pragma unroll
  for (int nt = 0; nt < 4; nt++)
#pragma unroll
    for (int kc = 0; kc < 2; kc++)
      bq[nt][kc] = *(const bf16x8*)(qgp + nt * 1024 + kc * 32 + g * 8);

  bf16x8 vones;
#pragma unroll
  for (int i = 0; i < 8; i++) vones[i] = (__bf16)1.0f;
  const floatx4 fzero = {0.f, 0.f, 0.f, 0.f};

  floatx4 o[4][4] = {};
  floatx4 lacc[4] = {};

  // walking base pointers
  const unsigned short* vbp = vf + fbase + (size_t)(wk * 2) * 4096 + lane * 8;
  const unsigned short* kgp =
      kg + kbase + (size_t)(wid * 64 + srow) * 64 + chunk * 8;

#define STAGE_K(b)                                                               \
  {                                                                              \
    _Pragma("unroll") for (int j = 0; j < 8; j++) {                              \
      GLD_LDS16(kgp + j * 512, (char*)L + (b)*32768 + wid * 8192 + j * 1024);    \
    }                                                                            \
    kgp += 16384;                                                                \
  }

#define QKT(dst, base)                                                           \
  {                                                                              \
    _Pragma("unroll") for (int mt = 0; mt < 4; mt++) {                           \
      bf16x8 ak0 = *(const bf16x8*)((base) + (mt * 16 + r) * 64 + (g ^ r7) * 8); \
      bf16x8 ak1 =                                                               \
          *(const bf16x8*)((base) + (mt * 16 + r) * 64 + ((4 + g) ^ r7) * 8);    \
      _Pragma("unroll") for (int nt = 0; nt < 4; nt++) {                         \
        floatx4 t = mfma16(ak0, bq[nt][0], fzero);                               \
        dst[mt][nt] = mfma16(ak1, bq[nt][1], t);                                 \
      }                                                                          \
    }                                                                            \
  }

#define SOFTMAX(src, ap)                                                         \
  {                                                                              \
    _Pragma("unroll") for (int a = 0; a < 4; a++) {                              \
      float p[4][4];                                                             \
      _Pragma("unroll") for (int mt = 0; mt < 4; mt++)                           \
          _Pragma("unroll") for (int e = 0; e < 4; e++)                          \
              p[mt][e] = fexp2(src[mt][a][e]);                                   \
      _Pragma("unroll") for (int kc = 0; kc < 2; kc++) {                         \
        union { unsigned u[4]; bf16x8 v; } w;                                    \
        w.u[0] = pk2p(p[2 * kc][0], p[2 * kc][1]);                               \
        w.u[1] = pk2p(p[2 * kc][2], p[2 * kc][3]);                               \
        w.u[2] = pk2p(p[2 * kc + 1][0], p[2 * kc + 1][1]);                       \
        w.u[3] = pk2p(p[2 * kc + 1][2], p[2 * kc + 1][3]);                       \
        ap[a][kc] = w.v;                                                         \
      }                                                                          \
    }                                                                            \
  }

#define PV(ap, bv)                                                               \
  {                                                                              \
    _Pragma("unroll") for (int kc = 0; kc < 2; kc++)                             \
        _Pragma("unroll") for (int a = 0; a < 4; a++) {                          \
      lacc[a] = mfma16(ap[a][kc], vones, lacc[a]);                               \
      _Pragma("unroll") for (int b = 0; b < 4; b++)                              \
          o[a][b] = mfma16(ap[a][kc], bv[b][kc], o[a][b]);                       \
    }                                                                            \
  }

  STAGE_K(0)
  for (int rnd = 0; rnd < 8; rnd++) {
    const int buf = rnd & 1;
    __syncthreads();
    if (rnd + 1 < 8) STAGE_K(buf ^ 1)
    const unsigned short* Kt = Ksm + buf * 16384 + wk * 8192;

    // V fragments for sub 0 (early; latency hidden under both QK^T clusters)
    bf16x8 bv0[4][2];
#pragma unroll
    for (int b = 0; b < 4; b++)
#pragma unroll
      for (int kc = 0; kc < 2; kc++)
        bv0[b][kc] = *(const bf16x8*)(vbp + b * 1024 + kc * 512);

    // Both QK^T clusters back-to-back: fills the matrix pipe so SM0's VALU
    // runs under QKT1's drain (T15).
    floatx4 st0[4][4], st1[4][4];
    __builtin_amdgcn_s_setprio(1);
    QKT(st0, Kt)
    QKT(st1, Kt + 4096)
    __builtin_amdgcn_s_setprio(0);

    bf16x8 ap[4][2];
    SOFTMAX(st0, ap)

    // V fragments for sub 1 (issued here: PV0 covers the latency)
    bf16x8 bv1[4][2];
#pragma unroll
    for (int b = 0; b < 4; b++)
#pragma unroll
      for (int kc = 0; kc < 2; kc++)
        bv1[b][kc] = *(const bf16x8*)(vbp + 4096 + b * 1024 + kc * 512);

    __builtin_amdgcn_s_setprio(1);
    PV(ap, bv0)
    __builtin_amdgcn_s_setprio(0);

    SOFTMAX(st1, ap)  // runs under PV0's drain

    __builtin_amdgcn_s_setprio(1);
    PV(ap, bv1)
    __builtin_amdgcn_s_setprio(0);

    vbp += 16384;
  }
#undef STAGE_K
#undef QKT
#undef SOFTMAX
#undef PV

  // combine the two kv streams (pure adds) through LDS
  float* fP = (float*)L;            // 32 KB
  float* fL = (float*)(L + 32768);  // 8 KB
  unsigned short* Osm = (unsigned short*)(L + 40960);  // [2][64*72] 18432 B
  __syncthreads();
  if (wk == 1) {
#pragma unroll
    for (int a = 0; a < 4; a++) {
      *(floatx4*)&fL[wq * 1024 + a * 256 + lane * 4] = lacc[a];
#pragma unroll
      for (int b = 0; b < 4; b++)
        *(floatx4*)&fP[wq * 4096 + (a * 4 + b) * 256 + lane * 4] = o[a][b];
    }
  }
  __syncthreads();
  if (wk == 0) {
#pragma unroll
    for (int a = 0; a < 4; a++) {
      floatx4 lt = lacc[a] + *(floatx4*)&fL[wq * 1024 + a * 256 + lane * 4];
      floatx4 il;
#pragma unroll
      for (int e = 0; e < 4; e++) il[e] = 1.f / lt[e];
#pragma unroll
      for (int b = 0; b < 4; b++) {
        floatx4 oo = o[a][b] +
                     *(floatx4*)&fP[wq * 4096 + (a * 4 + b) * 256 + lane * 4];
#pragma unroll
        for (int e = 0; e < 4; e++)
          Osm[wq * 4608 + (a * 16 + g * 4 + e) * 72 + b * 16 + r] =
              f2b(oo[e] * il[e]);
      }
    }
  }
  __syncthreads();
  const int bb = bh >> 3, h = bh & 7;
#pragma unroll
  for (int it = 0; it < 4; it++) {
    int c = it * 256 + tid;
    int row = c >> 3, cc = c & 7;
    int wqi = row >> 6, r6 = row & 63;
    shortx8 v = *(const shortx8*)(Osm + wqi * 4608 + r6 * 72 + cc * 8);
    int tok = qt * 128 + row;
    *(shortx8*)(ao + ((size_t)(bb * 2048 + tok)) * 512 + h * 64 + cc * 8) = v;
  }
}

// ---------------------------------------------------------------- launcher
extern "C" void kernel_launch(void* const* d_in, const int* in_sizes, int n_in,
                              void* d_out, int out_size, void* d_ws, size_t ws_size,
                              hipStream_t stream) {
  const float* x = (const float*)d_in[0];      // [4,2048,512]
  const float* w_qkv = (const float*)d_in[1];  // [512,1536]
  const float* w_out = (const float*)d_in[2];  // [512,512]
  const float* b_out = (const float*)d_in[3];  // [512]
  float* out = (float*)d_out;                  // [4,2048,512] fp32

  unsigned short* wsp = (unsigned short*)d_ws;
  unsigned short* xb = wsp;                            // 8192*512
  unsigned short* wqkvt = xb + (size_t)8192 * 512;     // 1536*512
  unsigned short* woutt = wqkvt + (size_t)1536 * 512;  // 512*512
  unsigned short* qg = woutt + (size_t)512 * 512;      // row-major [bh][n][64]
  unsigned short* kg = qg + (size_t)32 * 2048 * 64;    // row-major [bh][n][64]
  unsigned short* vf = kg + (size_t)32 * 2048 * 64;    // frag-major sigma V^T
  unsigned short* ao = vf + (size_t)32 * 2048 * 64;    // [8192][512]

  prep<<<5120, 256, 0, stream>>>(x, w_qkv, w_out, xb, wqkvt, woutt);
  gemm_qkv<<<dim3(12, 64), 256, 0, stream>>>(xb, wqkvt, qg, kg, vf);
  attn<<<dim3(512), 256, 0, stream>>>(qg, kg, vf, ao);
  gemm_out<<<dim3(4, 128), 128, 0, stream>>>(ao, woutt, out, b_out);
}

// Round 14
// 143.850 us; speedup vs baseline: 1.2020x; 1.2020x over previous
//
#include <hip/hip_runtime.h>
#include <hip/hip_bf16.h>
#include <cstdint>

#define DEV __device__ __forceinline__

typedef __attribute__((ext_vector_type(8))) __bf16 bf16x8;
typedef __attribute__((ext_vector_type(4))) float floatx4;
typedef __attribute__((ext_vector_type(4))) short shortx4;
typedef __attribute__((ext_vector_type(8))) short shortx8;

// 0.125 (= dim_head^-0.5) * log2(e): fold scale AND base-2 conversion into Q.
constexpr float QSCALE = 0.18033688011112042f;

// Manual RTNE f32->bf16 -- kept for prep (x, weights) and attn output.
// Rounds 6/7 proved gfx950's v_cvt_pk_bf16_f32 is NOT RTNE (1 output-ULP
// systematic bias, 0.03 absmax, 5x threshold) -- never reintroduce it.
DEV unsigned short f2b(float f) {
  union { float f; unsigned u; } v; v.f = f;
  return (unsigned short)((v.u + 0x7fffu + ((v.u >> 16) & 1u)) >> 16);  // RTNE
}

// Half-up rounding (no tie-to-even): differs from RTNE only on exact ties
// (prob ~2^-16/value), error still <= 0.5 ULP -- validated rounds 9/11
// (absmax unchanged at 0.00195). ~3x fewer VALU ops than manual RTNE.
DEV unsigned short f2bp(float f) {
  union { float f; unsigned u; } v; v.f = f;
  return (unsigned short)((v.u + 0x8000u) >> 16);
}

DEV unsigned pk2p(float a, float b) {
  union { float f; unsigned u; } x, y; x.f = a; y.f = b;
  return ((x.u + 0x8000u) >> 16) | ((y.u + 0x8000u) & 0xffff0000u);
}

#if defined(__has_builtin) && __has_builtin(__builtin_amdgcn_exp2f)
DEV float fexp2(float x) { return __builtin_amdgcn_exp2f(x); }
#else
DEV float fexp2(float x) { return exp2f(x); }
#endif

DEV floatx4 mfma16(bf16x8 a, bf16x8 b, floatx4 c) {
  return __builtin_amdgcn_mfma_f32_16x16x32_bf16(a, b, c, 0, 0, 0);
}

#define GLD_LDS16(gp, lp)                                                          \
  __builtin_amdgcn_global_load_lds(                                                \
      (const __attribute__((address_space(1))) void*)(gp),                         \
      (__attribute__((address_space(3))) void*)(lp), 16, 0, 0)

// ---------------------------------------------------------------- prep
// Fused: bf16-convert of x (blocks [0,4096)) + transpose-convert of both
// weight matrices (blocks [4096,5120)). One dispatch instead of two.
// Exact RTNE here (inputs feed two GEMM stages -- keep rounding canonical).
__global__ void prep(const float* __restrict__ x,
                     const float* __restrict__ w_qkv,
                     const float* __restrict__ w_out,
                     unsigned short* __restrict__ xb,
                     unsigned short* __restrict__ wqkvt,
                     unsigned short* __restrict__ woutt) {
  __shared__ float tile[32][33];
  if (blockIdx.x < 4096) {
    int i = blockIdx.x * 256 + threadIdx.x;
    floatx4 f = ((const floatx4*)x)[i];
    shortx4 s;
    s[0] = (short)f2b(f[0]); s[1] = (short)f2b(f[1]);
    s[2] = (short)f2b(f[2]); s[3] = (short)f2b(f[3]);
    ((shortx4*)xb)[i] = s;
    return;
  }
  int id = blockIdx.x - 4096;
  int bxr = id & 63, by = id >> 6;
  const float* in; unsigned short* out; int C, bx;
  if (bxr < 48) { in = w_qkv; out = wqkvt; C = 1536; bx = bxr; }
  else { in = w_out; out = woutt; C = 512; bx = bxr - 48; }
  const int R = 512;
  int tx = threadIdx.x & 31, ty = threadIdx.x >> 5;
  int r0 = by * 32, c0 = bx * 32;
#pragma unroll
  for (int i = 0; i < 4; i++) {
    int rr = ty + i * 8;
    tile[rr][tx] = in[(size_t)(r0 + rr) * C + c0 + tx];
  }
  __syncthreads();
#pragma unroll
  for (int i = 0; i < 4; i++) {
    int rr = ty + i * 8;
    out[(size_t)(c0 + rr) * R + r0 + tx] = f2b(tile[tx][rr]);
  }
}

// ---------------------------------------------------------------- QKV GEMM
// C = A * Bt^T. A [8192][512], Bt [1536][512]. 128x128 tile, BK=32, dbuf.
// grid (12,64) = 768 blocks, 3/CU co-resident. XCD-chunked block swizzle
// (768%8==0 -> bijective): XCD k runs flat ids [96k,96k+96) = 8 M-rows x
// all 12 N-cols -> whole B (1.5 MB) + 8 A-panels (1 MB) stay L2-hot.
// Epilogue conversions use half-up rounding (round-9/11-validated).
// Outputs:
//   q: row-major [bh][2048][64] (pre-scaled by QSCALE)
//   k: row-major [bh][2048][64]
//   v: sigma-permuted frag-major V^T [2048/64][b(4)][kc(2)][lane][8]
__global__ __launch_bounds__(256, 3) void gemm_qkv(
    const unsigned short* __restrict__ A, const unsigned short* __restrict__ Bt,
    unsigned short* __restrict__ qg, unsigned short* __restrict__ kg,
    unsigned short* __restrict__ vf) {
  __shared__ __align__(16) unsigned short smem[17408];  // 34816 B
  const int tid = threadIdx.x;
  const int lane = tid & 63, wid = tid >> 6;
  const int g = lane >> 4, r = lane & 15;
  const int flat = blockIdx.y * 12 + blockIdx.x;
  const int sw = (flat & 7) * 96 + (flat >> 3);
  const int bx = sw % 12, by = sw / 12;
  const int m0 = by * 128, n0 = bx * 128;
  const int wm = (wid & 1) * 64, wn = (wid >> 1) * 64;
  const int K = 512;

  floatx4 acc[4][4] = {};

  int rowA[2], kbA[2];
#pragma unroll
  for (int i = 0; i < 2; i++) {
    int c = i * 256 + tid;
    rowA[i] = c >> 2;
    kbA[i] = (c & 3) ^ ((rowA[i] >> 1) & 3);
  }

#define STAGE_G(kt, b)                                                           \
  {                                                                              \
    _Pragma("unroll") for (int i = 0; i < 2; i++) {                              \
      GLD_LDS16(A + (size_t)(m0 + rowA[i]) * K + (kt) + kbA[i] * 8,              \
                (char*)smem + (b)*8192 + i * 4096 + wid * 1024);                 \
      GLD_LDS16(Bt + (size_t)(n0 + rowA[i]) * K + (kt) + kbA[i] * 8,             \
                (char*)smem + 16384 + (b)*8192 + i * 4096 + wid * 1024);         \
    }                                                                            \
  }

  STAGE_G(0, 0)
  for (int it = 0; it < 16; it++) {
    const int buf = it & 1;
    __syncthreads();
    if (it + 1 < 16) STAGE_G((it + 1) * 32, buf ^ 1)
    const unsigned short* Xs = smem + buf * 4096;
    const unsigned short* Ws = smem + 8192 + buf * 4096;
    bf16x8 a[4], b[4];
#pragma unroll
    for (int t = 0; t < 4; t++) {
      int rw = wm + t * 16 + r;
      a[t] = *(const bf16x8*)(Xs + rw * 32 + (g ^ ((rw >> 1) & 3)) * 8);
      int rb = wn + t * 16 + r;
      b[t] = *(const bf16x8*)(Ws + rb * 32 + (g ^ ((rb >> 1) & 3)) * 8);
    }
#pragma unroll
    for (int mt = 0; mt < 4; mt++)
#pragma unroll
      for (int nt = 0; nt < 4; nt++)
        acc[mt][nt] = mfma16(a[mt], b[nt], acc[mt][nt]);
  }
#undef STAGE_G

  const int which = bx >> 2;  // 0=q 1=k 2=v (block-uniform)
  if (which == 2) {
    // fragment-major sigma-permuted V^T, 16B register stores
    const int tokbase = m0 + wm;  // 64-aligned
    const int bb = tokbase >> 11, vt = (tokbase & 2047) >> 6;
#pragma unroll
    for (int nt = 0; nt < 4; nt++) {
      int vcol = n0 + wn + nt * 16 + r - 1024;
      int h = vcol >> 6;  // uniform over r
      size_t hb = (size_t)(bb * 8 + h) * 131072 + (size_t)vt * 4096 + nt * 1024 +
                  (g * 16 + r) * 8;
#pragma unroll
      for (int kc = 0; kc < 2; kc++) {
        union { unsigned u[4]; shortx8 v; } w;
        w.u[0] = pk2p(acc[2 * kc][nt][0], acc[2 * kc][nt][1]);
        w.u[1] = pk2p(acc[2 * kc][nt][2], acc[2 * kc][nt][3]);
        w.u[2] = pk2p(acc[2 * kc + 1][nt][0], acc[2 * kc + 1][nt][1]);
        w.u[3] = pk2p(acc[2 * kc + 1][nt][2], acc[2 * kc + 1][nt][3]);
        *(shortx8*)(vf + hb + kc * 512) = w.v;
      }
    }
  } else {
    const float sc = (which == 0) ? QSCALE : 1.f;
    unsigned short* dst = (which == 0) ? qg : kg;  // both row-major [bh][n][64]
    __syncthreads();
#pragma unroll
    for (int mt = 0; mt < 4; mt++)
#pragma unroll
      for (int nt = 0; nt < 4; nt++) {
        int col = wn + nt * 16 + r;
#pragma unroll
        for (int e = 0; e < 4; e++)
          smem[(wm + mt * 16 + g * 4 + e) * 136 + col] = f2bp(acc[mt][nt][e] * sc);
      }
    __syncthreads();
#pragma unroll
    for (int it = 0; it < 8; it++) {
      int c = it * 256 + tid;
      int row = c >> 4, cc = c & 15;
      shortx8 v = *(const shortx8*)(smem + row * 136 + cc * 8);
      int gq = n0 + cc * 8;
      int h = (gq >> 6) & 7, d0 = gq & 63;
      int tok = m0 + row, bb = tok >> 11, n = tok & 2047;
      *(shortx8*)(dst + ((size_t)(bb * 8 + h) * 2048 + n) * 64 + d0) = v;
    }
  }
}

// ---------------------------------------------------------------- out GEMM
// C = A * Bt^T + bias. A [8192][512] bf16, Bt [512][512] bf16, out fp32.
// 64x128 tile, BK=32, dbuf, 128 threads / 2 waves, wave = 64x64 output ->
// 16 MFMA per 8 ds_read per iter. LDS: A 8 KiB dbuf + B 16 KiB dbuf =
// 24 KiB -> LB(128,3) ~6 blocks/CU. grid (4,128). LAUNCH WITH 128 THREADS.
// XCD-chunked swizzle (512%8==0 -> bijective digit swap).
__global__ __launch_bounds__(128, 3) void gemm_out(
    const unsigned short* __restrict__ A, const unsigned short* __restrict__ Bt,
    float* __restrict__ outF, const float* __restrict__ bias) {
  __shared__ __align__(16) unsigned short smem[12288];  // 24576 B
  const int tid = threadIdx.x;
  const int lane = tid & 63, wid = tid >> 6;
  const int g = lane >> 4, r = lane & 15;
  const int flat = blockIdx.y * 4 + blockIdx.x;
  const int sw = (flat & 7) * 64 + (flat >> 3);
  const int bx = sw & 3, by = sw >> 2;
  const int m0 = by * 64, n0 = bx * 128;
  const int wn = wid * 64;
  const int K = 512;

  floatx4 acc[4][4] = {};

  int rowA[2], kA[2];
#pragma unroll
  for (int i = 0; i < 2; i++) {
    int c = i * 128 + tid;
    rowA[i] = c >> 2;
    kA[i] = (c & 3) ^ ((rowA[i] >> 1) & 3);
  }
  int rowB[4], kB[4];
#pragma unroll
  for (int i = 0; i < 4; i++) {
    int c = i * 128 + tid;
    rowB[i] = c >> 2;
    kB[i] = (c & 3) ^ ((rowB[i] >> 1) & 3);
  }

#define STAGE_O(kt, b)                                                           \
  {                                                                              \
    _Pragma("unroll") for (int i = 0; i < 2; i++)                                \
        GLD_LDS16(A + (size_t)(m0 + rowA[i]) * K + (kt) + kA[i] * 8,             \
                  (char*)smem + (b)*4096 + i * 2048 + wid * 1024);               \
    _Pragma("unroll") for (int i = 0; i < 4; i++)                                \
        GLD_LDS16(Bt + (size_t)(n0 + rowB[i]) * K + (kt) + kB[i] * 8,            \
                  (char*)smem + 8192 + (b)*8192 + i * 2048 + wid * 1024);        \
  }

  STAGE_O(0, 0)
  for (int it = 0; it < 16; it++) {
    const int buf = it & 1;
    __syncthreads();
    if (it + 1 < 16) STAGE_O((it + 1) * 32, buf ^ 1)
    const unsigned short* Xs = smem + buf * 2048;
    const unsigned short* Ws = smem + 4096 + buf * 4096;
    bf16x8 a[4], b[4];
#pragma unroll
    for (int t = 0; t < 4; t++) {
      int rw = t * 16 + r;
      a[t] = *(const bf16x8*)(Xs + rw * 32 + (g ^ ((rw >> 1) & 3)) * 8);
      int rb = wn + t * 16 + r;
      b[t] = *(const bf16x8*)(Ws + rb * 32 + (g ^ ((rb >> 1) & 3)) * 8);
    }
#pragma unroll
    for (int mt = 0; mt < 4; mt++)
#pragma unroll
      for (int nt = 0; nt < 4; nt++)
        acc[mt][nt] = mfma16(a[mt], b[nt], acc[mt][nt]);
  }
#undef STAGE_O

  float* ftile = (float*)smem;  // [64][68] = 17408 B, fits in 24576
  __syncthreads();
#pragma unroll
  for (int pass = 0; pass < 2; pass++) {
    if (wid == pass) {
#pragma unroll
      for (int mt = 0; mt < 4; mt++)
#pragma unroll
        for (int nt = 0; nt < 4; nt++)
#pragma unroll
          for (int e = 0; e < 4; e++)
            ftile[(mt * 16 + g * 4 + e) * 68 + nt * 16 + r] = acc[mt][nt][e];
    }
    __syncthreads();
#pragma unroll
    for (int it = 0; it < 8; it++) {
      int c = it * 128 + tid;
      int lr = c >> 4, cc = c & 15;
      floatx4 v = *(const floatx4*)(ftile + lr * 68 + cc * 4);
      int col = n0 + pass * 64 + cc * 4;
      v += *(const floatx4*)(bias + col);
      *(floatx4*)(outF + (size_t)(m0 + lr) * 512 + col) = v;
    }
    __syncthreads();
  }
}

// ---------------------------------------------------------------- flash attention
// Best-measured configuration (rounds 9/11, 144.9 us total; round-13's T15
// 2-deep pipeline REVERTED -- it spilled st1 to scratch: VGPR 128 + 125 MB
// WRITE_SIZE, attn 49->76 us. The 4-wave layout lacks the VGPR headroom
// m214v36's 1-wave structure had).
// grid 512 blocks XCD-swizzled (each XCD owns 4 bh -> ~3 MB K/V/Q L2-hot),
// LB(256,2), 64 KiB LDS, exactly 2 blocks/CU, no tail.
// Block = 128 q rows x one bh. 4 waves: wq = q-half (64 rows), wk = kv
// stream (128 kv per round, 2 x 64kv subs). K staged via global_load_lds
// into double-buffered XOR-swizzled LDS (256 kv/round, 8 rounds).
// Q row-major direct loads, fzero C-operand QK^T, bv loaded early per sub,
// walking pointers, setprio, no-max softmax, pk2p P-packing, l via MFMA(P,1).
__global__ __launch_bounds__(256, 2) void attn(
    const unsigned short* __restrict__ qg, const unsigned short* __restrict__ kg,
    const unsigned short* __restrict__ vf, unsigned short* __restrict__ ao) {
  __shared__ __align__(16) char L[65536];
  unsigned short* Ksm = (unsigned short*)L;  // [2 buf][256 kv][64 d]
  const int tid = threadIdx.x, lane = tid & 63, wid = tid >> 6;
  const int g = lane >> 4, r = lane & 15, r7 = r & 7;
  const int wq = wid & 1, wk = wid >> 1;
  // XCD-bijective swizzle: slot&7 = XCD; each XCD owns bh in [xcd*4, xcd*4+4)
  const int slot = blockIdx.x;
  const int bh = ((slot & 7) << 2) | ((slot >> 3) & 3);
  const int qt = slot >> 5;  // 0..15, 128-row q tile
  const size_t kbase = (size_t)bh * (2048 * 64);  // row-major K and Q
  const size_t fbase = (size_t)bh * 131072;       // frag-major v
  const int srow = lane >> 3;
  const int chunk = (lane & 7) ^ (srow & 7);

  // Q fragments from row-major [bh][2048][64]: B-frag lane (g,r) needs
  // Q[qrow0 + nt*16 + r][kc*32 + g*8 .. +8]
  const unsigned short* qgp =
      qg + kbase + (size_t)(qt * 128 + wq * 64 + r) * 64;
  bf16x8 bq[4][2];
#pragma unroll
  for (int nt = 0; nt < 4; nt++)
#pragma unroll
    for (int kc = 0; kc < 2; kc++)
      bq[nt][kc] = *(const bf16x8*)(qgp + nt * 1024 + kc * 32 + g * 8);

  bf16x8 vones;
#pragma unroll
  for (int i = 0; i < 8; i++) vones[i] = (__bf16)1.0f;
  const floatx4 fzero = {0.f, 0.f, 0.f, 0.f};

  floatx4 o[4][4] = {};
  floatx4 lacc[4] = {};

  // walking base pointers
  const unsigned short* vbp = vf + fbase + (size_t)(wk * 2) * 4096 + lane * 8;
  const unsigned short* kgp =
      kg + kbase + (size_t)(wid * 64 + srow) * 64 + chunk * 8;

#define STAGE_K(b)                                                               \
  {                                                                              \
    _Pragma("unroll") for (int j = 0; j < 8; j++) {                              \
      GLD_LDS16(kgp + j * 512, (char*)L + (b)*32768 + wid * 8192 + j * 1024);    \
    }                                                                            \
    kgp += 16384;                                                                \
  }

  STAGE_K(0)
  for (int rnd = 0; rnd < 8; rnd++) {
    const int buf = rnd & 1;
    __syncthreads();
    if (rnd + 1 < 8) STAGE_K(buf ^ 1)
    const unsigned short* Kt = Ksm + buf * 16384 + wk * 8192;
#pragma unroll
    for (int sub = 0; sub < 2; sub++) {
      const unsigned short* Ks_ = Kt + sub * 4096;

      // V fragments for this 64-kv step, issued EARLY (vmcnt drains under
      // QK^T + softmax; consumed by PV)
      bf16x8 bv[4][2];
#pragma unroll
      for (int b = 0; b < 4; b++)
#pragma unroll
        for (int kc = 0; kc < 2; kc++)
          bv[b][kc] = *(const bf16x8*)(vbp + sub * 4096 + b * 1024 + kc * 512);

      // S^T [kv 64][q 64]: col=q(r), row=kv(g*4+e + 16*mt)
      floatx4 st[4][4];
      __builtin_amdgcn_s_setprio(1);
#pragma unroll
      for (int mt = 0; mt < 4; mt++) {
        bf16x8 ak0 = *(const bf16x8*)(Ks_ + (mt * 16 + r) * 64 + (g ^ r7) * 8);
        bf16x8 ak1 =
            *(const bf16x8*)(Ks_ + (mt * 16 + r) * 64 + ((4 + g) ^ r7) * 8);
#pragma unroll
        for (int nt = 0; nt < 4; nt++) {
          floatx4 t = mfma16(ak0, bq[nt][0], fzero);
          st[mt][nt] = mfma16(ak1, bq[nt][1], t);
        }
      }
      __builtin_amdgcn_s_setprio(0);

      // p = exp2(s) (no-max softmax; |s| bounded), in-lane pack to A-frags
      bf16x8 ap[4][2];
#pragma unroll
      for (int a = 0; a < 4; a++) {
        float p[4][4];
#pragma unroll
        for (int mt = 0; mt < 4; mt++)
#pragma unroll
          for (int e = 0; e < 4; e++) p[mt][e] = fexp2(st[mt][a][e]);
#pragma unroll
        for (int kc = 0; kc < 2; kc++) {
          union { unsigned u[4]; bf16x8 v; } w;
          w.u[0] = pk2p(p[2 * kc][0], p[2 * kc][1]);
          w.u[1] = pk2p(p[2 * kc][2], p[2 * kc][3]);
          w.u[2] = pk2p(p[2 * kc + 1][0], p[2 * kc + 1][1]);
          w.u[3] = pk2p(p[2 * kc + 1][2], p[2 * kc + 1][3]);
          ap[a][kc] = w.v;
        }
      }

      // O += P*V, l += P*1
      __builtin_amdgcn_s_setprio(1);
#pragma unroll
      for (int kc = 0; kc < 2; kc++)
#pragma unroll
        for (int a = 0; a < 4; a++) {
          lacc[a] = mfma16(ap[a][kc], vones, lacc[a]);
#pragma unroll
          for (int b = 0; b < 4; b++)
            o[a][b] = mfma16(ap[a][kc], bv[b][kc], o[a][b]);
        }
      __builtin_amdgcn_s_setprio(0);
    }
    vbp += 16384;
  }
#undef STAGE_K

  // combine the two kv streams (pure adds) through LDS
  float* fP = (float*)L;            // 32 KB
  float* fL = (float*)(L + 32768);  // 8 KB
  unsigned short* Osm = (unsigned short*)(L + 40960);  // [2][64*72] 18432 B
  __syncthreads();
  if (wk == 1) {
#pragma unroll
    for (int a = 0; a < 4; a++) {
      *(floatx4*)&fL[wq * 1024 + a * 256 + lane * 4] = lacc[a];
#pragma unroll
      for (int b = 0; b < 4; b++)
        *(floatx4*)&fP[wq * 4096 + (a * 4 + b) * 256 + lane * 4] = o[a][b];
    }
  }
  __syncthreads();
  if (wk == 0) {
#pragma unroll
    for (int a = 0; a < 4; a++) {
      floatx4 lt = lacc[a] + *(floatx4*)&fL[wq * 1024 + a * 256 + lane * 4];
      floatx4 il;
#pragma unroll
      for (int e = 0; e < 4; e++) il[e] = 1.f / lt[e];
#pragma unroll
      for (int b = 0; b < 4; b++) {
        floatx4 oo = o[a][b] +
                     *(floatx4*)&fP[wq * 4096 + (a * 4 + b) * 256 + lane * 4];
#pragma unroll
        for (int e = 0; e < 4; e++)
          Osm[wq * 4608 + (a * 16 + g * 4 + e) * 72 + b * 16 + r] =
              f2b(oo[e] * il[e]);
      }
    }
  }
  __syncthreads();
  const int bb = bh >> 3, h = bh & 7;
#pragma unroll
  for (int it = 0; it < 4; it++) {
    int c = it * 256 + tid;
    int row = c >> 3, cc = c & 7;
    int wqi = row >> 6, r6 = row & 63;
    shortx8 v = *(const shortx8*)(Osm + wqi * 4608 + r6 * 72 + cc * 8);
    int tok = qt * 128 + row;
    *(shortx8*)(ao + ((size_t)(bb * 2048 + tok)) * 512 + h * 64 + cc * 8) = v;
  }
}

// ---------------------------------------------------------------- launcher
extern "C" void kernel_launch(void* const* d_in, const int* in_sizes, int n_in,
                              void* d_out, int out_size, void* d_ws, size_t ws_size,
                              hipStream_t stream) {
  const float* x = (const float*)d_in[0];      // [4,2048,512]
  const float* w_qkv = (const float*)d_in[1];  // [512,1536]
  const float* w_out = (const float*)d_in[2];  // [512,512]
  const float* b_out = (const float*)d_in[3];  // [512]
  float* out = (float*)d_out;                  // [4,2048,512] fp32

  unsigned short* wsp = (unsigned short*)d_ws;
  unsigned short* xb = wsp;                            // 8192*512
  unsigned short* wqkvt = xb + (size_t)8192 * 512;     // 1536*512
  unsigned short* woutt = wqkvt + (size_t)1536 * 512;  // 512*512
  unsigned short* qg = woutt + (size_t)512 * 512;      // row-major [bh][n][64]
  unsigned short* kg = qg + (size_t)32 * 2048 * 64;    // row-major [bh][n][64]
  unsigned short* vf = kg + (size_t)32 * 2048 * 64;    // frag-major sigma V^T
  unsigned short* ao = vf + (size_t)32 * 2048 * 64;    // [8192][512]

  prep<<<5120, 256, 0, stream>>>(x, w_qkv, w_out, xb, wqkvt, woutt);
  gemm_qkv<<<dim3(12, 64), 256, 0, stream>>>(xb, wqkvt, qg, kg, vf);
  attn<<<dim3(512), 256, 0, stream>>>(qg, kg, vf, ao);
  gemm_out<<<dim3(4, 128), 128, 0, stream>>>(ao, woutt, out, b_out);
}